// Round 8
// baseline (302.350 us; speedup 1.0000x reference)
//
#include <hip/hip_runtime.h>
#include <math.h>

// RWKV single-token forward — ONE persistent kernel, "tagged-word" dataflow.
// Every cross-block value is published as ONE 8-byte word {epoch, float} via a
// relaxed agent-scope 64-bit atomic store (single-snapshot => tag-fresh implies
// payload-fresh; no fences, no flag+data two-step, no writer-side drains).
// The grid barrier IS the data gather: each thread polls its assigned words.
// LN stats (per-block sum/sumsq) are published as 2 extra words per block and
// reduced from 512 partials during the gather — the per-phase handshake is one
// LLC round trip + one LDS barrier.
// Weights: round-4 register window prefetch (issued right after each phase's
// dots, covered by the next gather poll).

typedef unsigned long long u64;

constexpr int E = 1024;
constexpr int H = 4096;
constexpr int V = 50277;
constexpr int L = 12;
constexpr int NBLK = 256;
constexpr int NTHR = 512;
constexpr float LN_EPS = 9.999999747378752e-06f;

#define SCOPE_AGENT __HIP_MEMORY_SCOPE_AGENT

__device__ __forceinline__ u64 aload(const u64 *p) {
  return __hip_atomic_load(p, __ATOMIC_RELAXED, SCOPE_AGENT);
}
__device__ __forceinline__ void astore(u64 *p, u64 v) {
  __hip_atomic_store(p, v, __ATOMIC_RELAXED, SCOPE_AGENT);
}
__device__ __forceinline__ u64 mkw(unsigned ep, float f) {
  return ((u64)ep << 32) | (u64)__float_as_uint(f);
}
__device__ __forceinline__ float wpay(u64 v) { return __uint_as_float((unsigned)v); }
__device__ __forceinline__ bool freshw(u64 v, unsigned ep) {
  return (unsigned)(v >> 32) == ep;
}

// LDS-only barrier (no vmem drain -> weight prefetches stay in flight).
__device__ __forceinline__ void lds_sync() {
  asm volatile("s_waitcnt lgkmcnt(0)" ::: "memory");
  __builtin_amdgcn_s_barrier();
}

struct Args {
  const float *statea, *stateb, *statec, *stated, *pre;
  const float *ln1w, *ln1b, *ln2w, *ln2b;
  const float *ak, *ar, *av, *kk, *vv, *rr, *tf, *td, *ovv;
  const float *tmk, *tmr, *kf, *rf, *vf;
  const float *post0, *post1, *post2;
  const int *token;
  float *out;
  u64 *wu, *wsx, *ssx, *wkm, *wx, *sxs;
};

__device__ __forceinline__ float wred(float v) {
#pragma unroll
  for (int off = 32; off; off >>= 1) v += __shfl_down(v, off, 64);
  return v;
}

__device__ __forceinline__ float dot4(float4 w, float4 x) {
  return w.x * x.x + w.y * x.y + w.z * x.z + w.w * x.w;
}

// Poll 2 data words (elements 2tid, 2tid+1).
__device__ __forceinline__ float2 gather2(const u64 *wd, unsigned ep, int tid) {
  const u64 *p = wd + 2 * tid;
  u64 a0 = aload(p), a1 = aload(p + 1);
  while (!(freshw(a0, ep) & freshw(a1, ep))) {
    __builtin_amdgcn_s_sleep(1);
    a0 = aload(p); a1 = aload(p + 1);
  }
  return make_float2(wpay(a0), wpay(a1));
}

// Poll 2 data words + 1 stats word (even tid: sum partial, odd: sumsq partial).
__device__ __forceinline__ void gather2s(const u64 *wd, const u64 *st, unsigned ep,
                                         int tid, float2 &v, float &sp) {
  const u64 *p = wd + 2 * tid;
  const u64 *q = st + tid;
  u64 a0 = aload(p), a1 = aload(p + 1), a2 = aload(q);
  while (!(freshw(a0, ep) & freshw(a1, ep) & freshw(a2, ep))) {
    __builtin_amdgcn_s_sleep(1);
    a0 = aload(p); a1 = aload(p + 1); a2 = aload(q);
  }
  v = make_float2(wpay(a0), wpay(a1));
  sp = wpay(a2);
}

// Poll 8 data words (km elements 8tid..8tid+7).
__device__ __forceinline__ void gather8(const u64 *wd, unsigned ep, int tid,
                                        float4 &f0, float4 &f1) {
  const u64 *p = wd + 8 * tid;
  u64 b0, b1, b2, b3, b4, b5, b6, b7;
  for (;;) {
    b0 = aload(p);     b1 = aload(p + 1); b2 = aload(p + 2); b3 = aload(p + 3);
    b4 = aload(p + 4); b5 = aload(p + 5); b6 = aload(p + 6); b7 = aload(p + 7);
    bool ok = freshw(b0, ep) & freshw(b1, ep) & freshw(b2, ep) & freshw(b3, ep) &
              freshw(b4, ep) & freshw(b5, ep) & freshw(b6, ep) & freshw(b7, ep);
    if (ok) break;
    __builtin_amdgcn_s_sleep(1);
  }
  f0 = make_float4(wpay(b0), wpay(b1), wpay(b2), wpay(b3));
  f1 = make_float4(wpay(b4), wpay(b5), wpay(b6), wpay(b7));
}

// Reduce 512 stats partials (even tid: sum, odd: sumsq) -> (mean, rstd).
// Performs one lds_sync (also covers any LDS staging done before the call).
__device__ __forceinline__ float2 stats_from_partials(float sp, float *s_red,
                                                      int lane, int wid) {
#pragma unroll
  for (int m = 2; m <= 32; m <<= 1) sp += __shfl_xor(sp, m, 64);
  if (lane < 2) s_red[wid * 2 + lane] = sp;
  lds_sync();
  float ts = 0.f, ts2 = 0.f;
#pragma unroll
  for (int i = 0; i < 8; ++i) { ts += s_red[2 * i]; ts2 += s_red[2 * i + 1]; }
  float m = ts * (1.0f / E);
  float var = ts2 * (1.0f / E) - m * m;
  return make_float2(m, rsqrtf(var + LN_EPS));
}

// Full local stats (prologue only, x from preprocess row).
__device__ __forceinline__ float2 stats_full(float2 v, float *s_red, int lane, int wid) {
  float s = v.x + v.y, s2 = v.x * v.x + v.y * v.y;
#pragma unroll
  for (int m = 1; m <= 32; m <<= 1) {
    s += __shfl_xor(s, m, 64);
    s2 += __shfl_xor(s2, m, 64);
  }
  if (lane == 0) { s_red[wid * 2] = s; s_red[wid * 2 + 1] = s2; }
  lds_sync();
  float ts = 0.f, ts2 = 0.f;
#pragma unroll
  for (int i = 0; i < 8; ++i) { ts += s_red[2 * i]; ts2 += s_red[2 * i + 1]; }
  float m = ts * (1.0f / E);
  float var = ts2 * (1.0f / E) - m * m;
  return make_float2(m, rsqrtf(var + LN_EPS));
}

struct P1B {  // P1 prefetch bundle (loaded at previous P4's end)
  float4 w[6];
  float2 lw, lb, sa, kk, vv, rr;
  float tf, td, sb, sc;
};

__device__ __forceinline__ void load_p1(P1B &p, const Args &a, int l, int grow,
                                        int b0h, int tid, int blk) {
  const size_t lE = (size_t)l * E;
  const float4 *kr = reinterpret_cast<const float4 *>(a.ak + (lE + grow) * E);
  const float4 *vr = reinterpret_cast<const float4 *>(a.av + (lE + grow) * E);
  const float4 *rr4 = reinterpret_cast<const float4 *>(a.ar + (lE + grow) * E);
  p.w[0] = kr[b0h]; p.w[1] = kr[b0h + 64];
  p.w[2] = vr[b0h]; p.w[3] = vr[b0h + 64];
  p.w[4] = rr4[b0h]; p.w[5] = rr4[b0h + 64];
  p.lw = reinterpret_cast<const float2 *>(a.ln1w + lE)[tid];
  p.lb = reinterpret_cast<const float2 *>(a.ln1b + lE)[tid];
  p.sa = reinterpret_cast<const float2 *>(a.statea + lE)[tid];
  p.kk = reinterpret_cast<const float2 *>(a.kk + lE)[tid];
  p.vv = reinterpret_cast<const float2 *>(a.vv + lE)[tid];
  p.rr = reinterpret_cast<const float2 *>(a.rr + lE)[tid];
  if (tid < 4) {
    size_t o = lE + blk * 4 + tid;
    p.tf = a.tf[o]; p.td = a.td[o]; p.sb = a.stateb[o]; p.sc = a.statec[o];
  } else {
    p.tf = 0.f; p.td = 0.f; p.sb = 0.f; p.sc = 1.f;
  }
}

__device__ __forceinline__ void loadrow(float4 *d, const float4 *P, int r, int lane) {
  const float4 *p = P + (size_t)r * 256;
  d[0] = p[lane]; d[1] = p[lane + 64]; d[2] = p[lane + 128]; d[3] = p[lane + 192];
}

__global__ __launch_bounds__(NTHR, 2) void rwkv_fused(Args a) {
  __shared__ __align__(16) float s_a[4096];
  __shared__ __align__(16) float s_x[1024];
  __shared__ float s_red[16];
  __shared__ float s_pp[24];
  __shared__ float s_rt[4];

  const int tid = threadIdx.x;
  const int lane = tid & 63;
  const int wid = tid >> 6;        // 0..7
  const int blk = blockIdx.x;
  const int rloc = wid >> 1;       // 0..3
  const int h = wid & 1;
  const int grow = blk * 4 + rloc; // global E-row
  const int b0h = h * 128 + lane;  // half-row float4 base (E=1024 rows)
  const int bv = h * 512 + lane;   // half-row float4 base (H=4096 rows)

  float *out_logits = a.out;
  float *out_aaa = a.out + V;
  float *out_bbb = out_aaa + L * E;
  float *out_ccc = out_bbb + L * E;
  float *out_ddd = out_ccc + L * E;

  const int tok = a.token[0];
  const float *pre_row = a.pre + (size_t)tok * E;
  const float4 *s4a = reinterpret_cast<const float4 *>(s_a);

  P1B p1;
  load_p1(p1, a, 0, grow, b0h, tid, blk);

#pragma unroll 1
  for (int l = 0; l < L; ++l) {
    const size_t lE = (size_t)l * E;
    const unsigned e1 = 4 * l + 1, e2 = 4 * l + 2, e3 = 4 * l + 3, e4 = 4 * l + 4;
    float4 pwo[2], pw3[10], pw4[8];
    float2 e3w, e3b, e3sd, e3tk, e3tr;

    // ================= P1: LN1 + k/v/r matvecs + wkv =================
    {
      float2 xv; float2 st;
      if (l == 0) {
        xv = reinterpret_cast<const float2 *>(pre_row)[tid];
        reinterpret_cast<float2 *>(s_x)[tid] = xv;
        st = stats_full(xv, s_red, lane, wid);
      } else {
        float sp;
        gather2s(a.wx, a.sxs, 4 * l, tid, xv, sp);
        reinterpret_cast<float2 *>(s_x)[tid] = xv;
        st = stats_from_partials(sp, s_red, lane, wid);
      }
      float2 xy = make_float2((xv.x - st.x) * st.y * p1.lw.x + p1.lb.x,
                              (xv.y - st.x) * st.y * p1.lw.y + p1.lb.y);
      if ((tid >> 1) == blk) {
        out_aaa[lE + 2 * tid] = xy.x;
        out_aaa[lE + 2 * tid + 1] = xy.y;
      }
      reinterpret_cast<float2 *>(s_a)[tid] =
          make_float2(xy.x + p1.kk.x * p1.sa.x, xy.y + p1.kk.y * p1.sa.y);
      reinterpret_cast<float2 *>(s_a + 1024)[tid] =
          make_float2(xy.x + p1.vv.x * p1.sa.x, xy.y + p1.vv.y * p1.sa.y);
      reinterpret_cast<float2 *>(s_a + 2048)[tid] =
          make_float2(xy.x + p1.rr.x * p1.sa.x, xy.y + p1.rr.y * p1.sa.y);
      lds_sync();
      float accK = dot4(p1.w[0], s4a[b0h]) + dot4(p1.w[1], s4a[b0h + 64]);
      float accV = dot4(p1.w[2], s4a[256 + b0h]) + dot4(p1.w[3], s4a[256 + b0h + 64]);
      float accR = dot4(p1.w[4], s4a[512 + b0h]) + dot4(p1.w[5], s4a[512 + b0h + 64]);
      accK = wred(accK); accV = wred(accV); accR = wred(accR);
      if (lane == 0) {
        s_pp[wid * 3 + 0] = accK;
        s_pp[wid * 3 + 1] = accV;
        s_pp[wid * 3 + 2] = accR;
      }
      lds_sync();
      // prefetch P2 weights (ovv half-row) — covered by P2's gather poll
      {
        const float4 *orow = reinterpret_cast<const float4 *>(a.ovv + (lE + grow) * E);
        pwo[0] = orow[b0h]; pwo[1] = orow[b0h + 64];
      }
      if (wid == 0) {
        int i = lane & 3;
        float K = s_pp[(2 * i) * 3] + s_pp[(2 * i + 1) * 3];
        float Vv = s_pp[(2 * i) * 3 + 1] + s_pp[(2 * i + 1) * 3 + 1];
        float R = s_pp[(2 * i) * 3 + 2] + s_pp[(2 * i + 1) * 3 + 2];
        float kx = expf(K), rx = expf(R) + 1.0f;
        float etf = expf(p1.tf), etd = expf(p1.td);
        float w_ = p1.sb + etf * kx * Vv;
        float d_ = p1.sc * rx + etf * kx * rx;
        float uv = w_ / (d_ + 0.001f);
        if (lane < 4) {
          size_t o = lE + blk * 4 + lane;
          astore(a.wu + blk * 4 + lane, mkw(e1, uv));
          out_bbb[o] = p1.sb * etd + kx * Vv;
          out_ccc[o] = p1.sc * etd + kx;
        }
      }
    }

    // ================= P2: sxx = x + ovv @ u =================
    {
      float2 u2 = gather2(a.wu, e1, tid);
      reinterpret_cast<float2 *>(s_a)[tid] = u2;
      lds_sync();
      float acc = dot4(pwo[0], s4a[b0h]) + dot4(pwo[1], s4a[b0h + 64]);
      float x4 = s_x[blk * 4 + (lane & 3)];  // read before publish (safe: our
                                             // s_x slots only overwritten after
                                             // our own publish below)
      acc = wred(acc);
      if (lane == 0) s_pp[wid] = acc;
      lds_sync();
      // prefetch P3 weights: kf 2 rows/wave + rf half-row + LN2/mix vectors
      {
        const float *kfb = a.kf + (size_t)l * H * E;
        const float4 *k0 = reinterpret_cast<const float4 *>(kfb + (size_t)(blk * 16 + wid) * E);
        const float4 *k1 = reinterpret_cast<const float4 *>(kfb + (size_t)(blk * 16 + 8 + wid) * E);
        pw3[0] = k0[lane];       pw3[1] = k0[lane + 64];
        pw3[2] = k0[lane + 128]; pw3[3] = k0[lane + 192];
        pw3[4] = k1[lane];       pw3[5] = k1[lane + 64];
        pw3[6] = k1[lane + 128]; pw3[7] = k1[lane + 192];
        const float4 *rrow = reinterpret_cast<const float4 *>(a.rf + (lE + grow) * E);
        pw3[8] = rrow[b0h]; pw3[9] = rrow[b0h + 64];
        e3w = reinterpret_cast<const float2 *>(a.ln2w + lE)[tid];
        e3b = reinterpret_cast<const float2 *>(a.ln2b + lE)[tid];
        e3sd = reinterpret_cast<const float2 *>(a.stated + lE)[tid];
        e3tk = reinterpret_cast<const float2 *>(a.tmk + lE)[tid];
        e3tr = reinterpret_cast<const float2 *>(a.tmr + lE)[tid];
      }
      if (wid == 0) {
        int i = lane & 3;
        float sxxv = x4 + s_pp[2 * i] + s_pp[2 * i + 1];
        float s0 = __shfl(sxxv, 0), s1 = __shfl(sxxv, 1);
        float s2v = __shfl(sxxv, 2), s3 = __shfl(sxxv, 3);
        float sum = s0 + s1 + s2v + s3;
        float ssq = s0 * s0 + s1 * s1 + s2v * s2v + s3 * s3;
        if (lane < 4) astore(a.wsx + blk * 4 + lane, mkw(e2, sxxv));
        if (lane == 0) astore(a.ssx + blk * 2 + 0, mkw(e2, sum));
        if (lane == 1) astore(a.ssx + blk * 2 + 1, mkw(e2, ssq));
      }
    }

    // ================= P3: LN2 + key_ffn + receptance_ffn =================
    {
      float2 sxv; float sp;
      gather2s(a.wsx, a.ssx, e2, tid, sxv, sp);
      reinterpret_cast<float2 *>(s_x)[tid] = sxv;
      float2 st = stats_from_partials(sp, s_red, lane, wid);
      float2 xx = make_float2((sxv.x - st.x) * st.y * e3w.x + e3b.x,
                              (sxv.y - st.x) * st.y * e3w.y + e3b.y);
      if ((tid >> 1) == blk) {
        out_ddd[lE + 2 * tid] = xx.x;
        out_ddd[lE + 2 * tid + 1] = xx.y;
      }
      reinterpret_cast<float2 *>(s_a)[tid] =
          make_float2(xx.x + e3tk.x * e3sd.x, xx.y + e3tk.y * e3sd.y);
      reinterpret_cast<float2 *>(s_a + 1024)[tid] =
          make_float2(xx.x + e3tr.x * e3sd.x, xx.y + e3tr.y * e3sd.y);
      lds_sync();
      float k0 = 0.f, k1 = 0.f;
#pragma unroll
      for (int it = 0; it < 4; ++it) {
        float4 xv4 = s4a[it * 64 + lane];
        k0 += dot4(pw3[it], xv4);
        k1 += dot4(pw3[4 + it], xv4);
      }
      float ar_ = dot4(pw3[8], s4a[256 + b0h]) + dot4(pw3[9], s4a[256 + b0h + 64]);
      k0 = wred(k0); k1 = wred(k1); ar_ = wred(ar_);
      if (lane == 0) {
        float t0 = fmaxf(k0, 0.f), t1 = fmaxf(k1, 0.f);
        astore(a.wkm + blk * 16 + wid, mkw(e3, t0 * t0));
        astore(a.wkm + blk * 16 + 8 + wid, mkw(e3, t1 * t1));
        s_pp[wid] = ar_;
      }
      lds_sync();
      // prefetch P4 weights: vf half-row
      {
        const float4 *vrow = reinterpret_cast<const float4 *>(a.vf + (lE + grow) * H);
        pw4[0] = vrow[bv];       pw4[1] = vrow[bv + 64];
        pw4[2] = vrow[bv + 128]; pw4[3] = vrow[bv + 192];
        pw4[4] = vrow[bv + 256]; pw4[5] = vrow[bv + 320];
        pw4[6] = vrow[bv + 384]; pw4[7] = vrow[bv + 448];
      }
      if (tid < 4) s_rt[tid] = expf(s_pp[2 * tid] + s_pp[2 * tid + 1]) + 1.0f;
    }

    // ================= P4: x_next = sxx + (vf @ km) / rt =================
    {
      float4 f0, f1;
      gather8(a.wkm, e3, tid, f0, f1);
      reinterpret_cast<float4 *>(s_a)[2 * tid] = f0;
      reinterpret_cast<float4 *>(s_a)[2 * tid + 1] = f1;
      lds_sync();
      float acc = 0.f;
#pragma unroll
      for (int it = 0; it < 8; ++it) acc += dot4(pw4[it], s4a[bv + it * 64]);
      float sx4 = s_x[blk * 4 + (lane & 3)];  // sxx, read before publish
      acc = wred(acc);
      if (lane == 0) s_pp[wid] = acc;
      lds_sync();
      // prefetch next layer's P1 bundle (or final LN vectors)
      if (l + 1 < L) {
        load_p1(p1, a, l + 1, grow, b0h, tid, blk);
      } else {
        p1.lw = reinterpret_cast<const float2 *>(a.post0)[tid];
        p1.lb = reinterpret_cast<const float2 *>(a.post1)[tid];
      }
      if (wid == 0) {
        int i = lane & 3;
        float xn = sx4 + (s_pp[2 * i] + s_pp[2 * i + 1]) / s_rt[i];
        float s0 = __shfl(xn, 0), s1 = __shfl(xn, 1);
        float s2v = __shfl(xn, 2), s3 = __shfl(xn, 3);
        float sum = s0 + s1 + s2v + s3;
        float ssq = s0 * s0 + s1 * s1 + s2v * s2v + s3 * s3;
        if (lane < 4) astore(a.wx + blk * 4 + lane, mkw(e4, xn));
        if (lane == 0) astore(a.sxs + blk * 2 + 0, mkw(e4, sum));
        if (lane == 1) astore(a.sxs + blk * 2 + 1, mkw(e4, ssq));
      }
    }
  }

  // ================= Final: LN + logits (double-buffered stream) =================
  {
    float2 xv; float sp;
    gather2s(a.wx, a.sxs, 4 * L, tid, xv, sp);
    float2 st = stats_from_partials(sp, s_red, lane, wid);
    reinterpret_cast<float2 *>(s_a)[tid] =
        make_float2((xv.x - st.x) * st.y * p1.lw.x + p1.lb.x,
                    (xv.y - st.x) * st.y * p1.lw.y + p1.lb.y);
    lds_sync();

    const float4 *P2 = reinterpret_cast<const float4 *>(a.post2);
    const int gw = blk * 8 + wid;  // 0..2047
    int r0 = gw, r1 = gw + 2048;
    float4 A0[4], A1[4];
    loadrow(A0, P2, r0, lane);
    loadrow(A1, P2, r1 < V ? r1 : r0, lane);
    while (true) {
      int n0 = r0 + 4096, n1 = n0 + 2048;
      bool more = n0 < V;
      float4 B0[4], B1[4];
      if (more) {
        loadrow(B0, P2, n0, lane);
        loadrow(B1, P2, n1 < V ? n1 : n0, lane);
      }
      float a0 = dot4(A0[0], s4a[lane]) + dot4(A0[1], s4a[lane + 64]) +
                 dot4(A0[2], s4a[lane + 128]) + dot4(A0[3], s4a[lane + 192]);
      float a1 = dot4(A1[0], s4a[lane]) + dot4(A1[1], s4a[lane + 64]) +
                 dot4(A1[2], s4a[lane + 128]) + dot4(A1[3], s4a[lane + 192]);
      a0 = wred(a0); a1 = wred(a1);
      if (lane == 0) {
        out_logits[r0] = a0;
        if (r1 < V) out_logits[r1] = a1;
      }
      if (!more) break;
#pragma unroll
      for (int q = 0; q < 4; ++q) { A0[q] = B0[q]; A1[q] = B1[q]; }
      r0 = n0; r1 = n1;
    }
  }
}

extern "C" void kernel_launch(void *const *d_in, const int *in_sizes, int n_in,
                              void *d_out, int out_size, void *d_ws, size_t ws_size,
                              hipStream_t stream) {
  (void)in_sizes; (void)n_in; (void)out_size; (void)ws_size;
  Args a;
  a.statea = (const float *)d_in[0];
  a.stateb = (const float *)d_in[1];
  a.statec = (const float *)d_in[2];
  a.stated = (const float *)d_in[3];
  a.pre    = (const float *)d_in[4];
  a.ln1w   = (const float *)d_in[5];
  a.ln1b   = (const float *)d_in[6];
  a.ln2w   = (const float *)d_in[7];
  a.ln2b   = (const float *)d_in[8];
  a.ak     = (const float *)d_in[9];
  a.ar     = (const float *)d_in[10];
  a.av     = (const float *)d_in[11];
  a.kk     = (const float *)d_in[12];
  a.vv     = (const float *)d_in[13];
  a.rr     = (const float *)d_in[14];
  a.tf     = (const float *)d_in[15];
  a.td     = (const float *)d_in[16];
  a.ovv    = (const float *)d_in[17];
  a.tmk    = (const float *)d_in[18];
  a.tmr    = (const float *)d_in[19];
  a.kf     = (const float *)d_in[20];
  a.rf     = (const float *)d_in[21];
  a.vf     = (const float *)d_in[22];
  a.post0  = (const float *)d_in[23];
  a.post1  = (const float *)d_in[24];
  a.post2  = (const float *)d_in[25];
  a.token  = (const int *)d_in[26];
  a.out    = (float *)d_out;

  u64 *wb = (u64 *)d_ws;
  a.wu  = wb;          // 1024 words  (u)
  a.wsx = wb + 1024;   // 1024 words  (sxx)
  a.ssx = wb + 2048;   // 512 words   (sxx stats)
  a.wkm = wb + 2560;   // 4096 words  (km)
  a.wx  = wb + 6656;   // 1024 words  (x)
  a.sxs = wb + 7680;   // 512 words   (x stats)
  // total 8192 words = 64 KB; zero tags each launch (graph-capture safe)
  hipMemsetAsync(d_ws, 0, 8192 * sizeof(u64), stream);
  rwkv_fused<<<NBLK, NTHR, 0, stream>>>(a);
}